// Round 1
// baseline (1145.902 us; speedup 1.0000x reference)
//
#include <hip/hip_runtime.h>
#include <math.h>

#define BS 128
#define GS 2000
#define E  128
#define KMAXI 4
#define CLIPV 10.0f
#define NEGV  -1.0e30f

typedef __bf16 bf16_t;
typedef __bf16 bf16x8 __attribute__((ext_vector_type(8)));
typedef float fx4 __attribute__((ext_vector_type(4)));

__device__ __forceinline__ float fast_sigmoid(float x){ return 1.0f/(1.0f+__expf(-x)); }
__device__ __forceinline__ float fast_tanhf(float x){
    float e = __expf(2.0f*x);
    return 1.0f - 2.0f/(e + 1.0f);
}

// ---------------------------------------------------------------- h partial sums (for mean)
__global__ void k_hpart(const float* __restrict__ h, float* __restrict__ hpart){
    int b = blockIdx.x, p = blockIdx.y, t = threadIdx.x; // t in [0,128)
    float acc = 0.f;
    int g0 = p*125, g1 = g0+125;                          // 16*125 = 2000
    const float* hp = h + ((size_t)b*GS)*E + t;
    for (int g=g0; g<g1; ++g) acc += hp[(size_t)g*E];
    hpart[(b*16+p)*E + t] = acc;
}

// ---------------------------------------------------------------- qinit + state/mask init
__global__ void k_setup(const float* __restrict__ hpart,
                        const float* __restrict__ W_init, const float* __restrict__ b_init,
                        const float* __restrict__ init_query,
                        float* __restrict__ q1s, float* __restrict__ q2s,
                        float* __restrict__ q1in, float* __restrict__ q2in,
                        int* __restrict__ state, unsigned char* __restrict__ mask)
{
    int b = blockIdx.x, t = threadIdx.x; // 128 threads
    __shared__ float hm[E];
    float s = 0.f;
    for (int p=0;p<16;++p) s += hpart[(b*16+p)*E + t];
    hm[t] = s * (1.0f/(float)GS);
    __syncthreads();
    float acc = b_init[t];
    for (int e=0;e<E;++e) acc += hm[e]*W_init[t*E+e];
    q1s[b*E+t]=acc; q2s[b*E+t]=acc;
    float iq = init_query[t];
    q1in[b*E+t]=iq; q2in[b*E+t]=iq;
    for (int g=t; g<GS; g+=E) mask[(size_t)b*GS+g]=0;
    if (t==0){
        int* st = state + b*32;
        st[0]=1;            // stopped = True (initial)
        st[1]=-1;           // nol
        for (int j=2;j<15;++j) st[j]=0;  // ai[4], kl[5], kr[4]
        st[15]=__float_as_int(0.0f);     // ll
    }
}

// ---------------------------------------------------------------- GRU + projections + combined matrices
__device__ __forceinline__ void gru_half(int b, int t,
    const float* __restrict__ qin, float* __restrict__ qs,
    const float* __restrict__ Wih, const float* __restrict__ Whh,
    const float* __restrict__ bih, const float* __restrict__ bhh,
    const float* __restrict__ WQa, const float* __restrict__ WQm,
    const float* __restrict__ WKa, const float* __restrict__ WKm,
    float* __restrict__ addv, bf16_t* __restrict__ Mt,
    float* xs, float* hs, float* qn, float* mul)
{
    xs[t] = qin[b*E+t]; hs[t] = qs[b*E+t];
    __syncthreads();
    float gr=bih[t], gz=bih[t+E], gn=bih[t+2*E];
    float hr=bhh[t], hz=bhh[t+E], hn=bhh[t+2*E];
    const float* wr = Wih + (size_t)t*E;       const float* vr = Whh + (size_t)t*E;
    const float* wz = Wih + (size_t)(t+E)*E;   const float* vz = Whh + (size_t)(t+E)*E;
    const float* wn = Wih + (size_t)(t+2*E)*E; const float* vn = Whh + (size_t)(t+2*E)*E;
    for (int e=0;e<E;++e){
        float x=xs[e], h0=hs[e];
        gr += x*wr[e];  gz += x*wz[e];  gn += x*wn[e];
        hr += h0*vr[e]; hz += h0*vz[e]; hn += h0*vn[e];
    }
    float r = fast_sigmoid(gr+hr);
    float z = fast_sigmoid(gz+hz);
    float n = fast_tanhf(gn + r*hn);
    float hnew = (1.f-z)*n + z*hs[t];
    qn[t] = hnew; qs[b*E+t] = hnew;
    __syncthreads();
    float a=0.f, m=0.f;
    const float* wa = WQa + (size_t)t*E; const float* wm = WQm + (size_t)t*E;
    for (int e=0;e<E;++e){ float qv=qn[e]; a += qv*wa[e]; m += qv*wm[e]; }
    addv[b*E+t] = a; mul[t] = m;
    __syncthreads();
    // M[f][e] = WKa[f,e] + WKm[f,e]*mul[f]   (f-major so MFMA B-frag loads are contiguous in e)
    for (int f=0; f<E; ++f){
        float v = WKa[(size_t)f*E+t] + WKm[(size_t)f*E+t]*mul[f];
        Mt[((size_t)(b*E+f))*E + t] = (bf16_t)v;
    }
    __syncthreads();
}

__global__ void k_gru(const float* __restrict__ q1in, const float* __restrict__ q2in,
    float* __restrict__ q1s, float* __restrict__ q2s,
    const float* __restrict__ Wih1, const float* __restrict__ Whh1,
    const float* __restrict__ bih1, const float* __restrict__ bhh1,
    const float* __restrict__ Wih2, const float* __restrict__ Whh2,
    const float* __restrict__ bih2, const float* __restrict__ bhh2,
    const float* __restrict__ WQ1, const float* __restrict__ WQ2,
    const float* __restrict__ WQ3, const float* __restrict__ WQ4,
    const float* __restrict__ WK1, const float* __restrict__ WK2,
    const float* __restrict__ WK3, const float* __restrict__ WK4,
    float* __restrict__ add1, float* __restrict__ add2,
    bf16_t* __restrict__ M1t, bf16_t* __restrict__ M2t)
{
    __shared__ float xs[E], hs[E], qn[E], mul[E];
    int b=blockIdx.x, t=threadIdx.x;
    gru_half(b,t,q1in,q1s, Wih1,Whh1,bih1,bhh1, WQ1,WQ3, WK1,WK3, add1,M1t, xs,hs,qn,mul);
    gru_half(b,t,q2in,q2s, Wih2,Whh2,bih2,bhh2, WQ2,WQ4, WK2,WK4, add2,M2t, xs,hs,qn,mul);
}

// ---------------------------------------------------------------- scores: per-b GEMM + tanh + V-dot
// logits_raw[b,g] = CLIP*tanh( sum_f V1[f]*tanh((h@M1)[g,f]+add1[f]) + sum_f V2[f]*tanh((h@M2)[g,f]+add2[f]) )
__global__ __launch_bounds__(256) void k_scores(
    const float* __restrict__ h,
    const bf16_t* __restrict__ M1t, const bf16_t* __restrict__ M2t,
    const float* __restrict__ add1, const float* __restrict__ add2,
    const float* __restrict__ V1, const float* __restrict__ V2,
    float* __restrict__ raw)
{
    int b    = blockIdx.y;
    int wave = threadIdx.x >> 6;
    int lane = threadIdx.x & 63;
    int qd   = lane >> 4, c = lane & 15;
    int g0   = blockIdx.x*64 + wave*16;

    // A-fragments: A[m=lane&15][k=quad*8+j] ; m is g-row within tile, k is e
    int grow = g0 + c; if (grow >= GS) grow = GS-1;
    const float* hrow = h + ((size_t)b*GS + grow)*E;
    bf16x8 afr[4];
    #pragma unroll
    for (int s=0;s<4;++s){
        const float* p = hrow + s*32 + qd*8;
        float4 u0 = *(const float4*)(p);
        float4 u1 = *(const float4*)(p+4);
        bf16x8 a;
        a[0]=(bf16_t)u0.x; a[1]=(bf16_t)u0.y; a[2]=(bf16_t)u0.z; a[3]=(bf16_t)u0.w;
        a[4]=(bf16_t)u1.x; a[5]=(bf16_t)u1.y; a[6]=(bf16_t)u1.z; a[7]=(bf16_t)u1.w;
        afr[s]=a;
    }

    const bf16x8* M1p = (const bf16x8*)(M1t + (size_t)b*E*E);
    const bf16x8* M2p = (const bf16x8*)(M2t + (size_t)b*E*E);

    float sp[4] = {0.f,0.f,0.f,0.f};
    #pragma unroll
    for (int tf=0; tf<8; ++tf){
        int f = tf*16 + c;              // B-frag: B[k][n], n = lane&15 -> f
        fx4 acc1 = {0.f,0.f,0.f,0.f};
        fx4 acc2 = {0.f,0.f,0.f,0.f};
        const bf16x8* r1 = M1p + (size_t)f*16;
        const bf16x8* r2 = M2p + (size_t)f*16;
        #pragma unroll
        for (int s=0;s<4;++s){
            acc1 = __builtin_amdgcn_mfma_f32_16x16x32_bf16(afr[s], r1[s*4+qd], acc1, 0,0,0);
            acc2 = __builtin_amdgcn_mfma_f32_16x16x32_bf16(afr[s], r2[s*4+qd], acc2, 0,0,0);
        }
        float a1 = add1[b*E+f], a2 = add2[b*E+f];
        float v1 = V1[f],      v2 = V2[f];
        #pragma unroll
        for (int r=0;r<4;++r){
            // C/D layout: row = quad*4+r (g), col = lane&15 (f)
            sp[r] += v1*fast_tanhf(acc1[r]+a1) + v2*fast_tanhf(acc2[r]+a2);
        }
    }
    // reduce over the 16 lanes (c) of each quad -> full sum over f
    #pragma unroll
    for (int r=0;r<4;++r){
        float s = sp[r];
        s += __shfl_xor(s, 1); s += __shfl_xor(s, 2);
        s += __shfl_xor(s, 4); s += __shfl_xor(s, 8);
        if (c==0){
            int g = g0 + qd*4 + r;
            if (g < GS) raw[(size_t)b*GS + g] = CLIPV * fast_tanhf(s);
        }
    }
}

// ---------------------------------------------------------------- per-step: log-softmax + bookkeeping
__global__ void k_step(int iter,
    const float* __restrict__ raw, const float* __restrict__ h,
    const int* __restrict__ rec, const int* __restrict__ vtime,
    const int* __restrict__ last_action, const int* __restrict__ fixed_action,
    unsigned char* __restrict__ mask, int* __restrict__ vtt,
    int* __restrict__ state, float* __restrict__ q1in, float* __restrict__ q2in,
    float* __restrict__ out)
{
    int b = blockIdx.x, t = threadIdx.x;   // 256 threads
    __shared__ float red[256];
    int* st = state + b*32;
    int old_stopped = st[0];
    int nol_old     = st[1];
    int ai0_old     = st[2];
    int la          = last_action[b];

    int action;
    if (iter==0) action = fixed_action[b*KMAXI];
    else         action = old_stopped ? ai0_old : fixed_action[b*KMAXI+iter];

    // ---- logsumexp over masked logits (mask is from previous iteration)
    float mx = -3.0e38f;
    for (int g=t; g<GS; g+=256){
        float l = raw[(size_t)b*GS+g];
        if (mask[(size_t)b*GS+g]) l = NEGV;
        if (iter==0 && g==la)     l = NEGV;
        mx = fmaxf(mx, l);
    }
    red[t]=mx; __syncthreads();
    for (int s=128;s>0;s>>=1){ if(t<s) red[t]=fmaxf(red[t],red[t+s]); __syncthreads(); }
    mx = red[0]; __syncthreads();
    float sm = 0.f;
    for (int g=t; g<GS; g+=256){
        float l = raw[(size_t)b*GS+g];
        if (mask[(size_t)b*GS+g]) l = NEGV;
        if (iter==0 && g==la)     l = NEGV;
        sm += __expf(l-mx);
    }
    red[t]=sm; __syncthreads();
    for (int s=128;s>0;s>>=1){ if(t<s) red[t]+=red[t+s]; __syncthreads(); }
    float lse = mx + __logf(red[0]);
    __syncthreads();

    float al = raw[(size_t)b*GS+action];
    if (mask[(size_t)b*GS+action]) al = NEGV;
    if (iter==0 && action==la)     al = NEGV;
    float loss = al - lse;

    int nna = rec[(size_t)b*GS+action];
    int eq  = (action == nol_old) ? 1 : 0;
    int new_stopped = (iter==0) ? eq : (old_stopped | eq);
    int ai0_new = (iter==0) ? action : ai0_old;
    int allow = (!new_stopped) && (nna == ai0_new);

    __syncthreads();   // everyone done READING old mask before anyone writes new mask

    // ---- vtt (computed once at iter 0, Python-mod semantics)
    if (iter==0){
        int va = vtime[(size_t)b*GS+action];
        for (int g=t; g<GS; g+=256){
            int d = vtime[(size_t)b*GS+g] - va;
            d %= GS; if (d<0) d += GS;
            vtt[(size_t)b*GS+g] = d;           // same-thread partition as mask loop below
        }
    }
    int vta = (iter==0) ? 0 : vtt[(size_t)b*GS+action];

    // ---- new mask
    for (int g=t; g<GS; g+=256){
        int vg = vtt[(size_t)b*GS+g];
        int m = (vg <= vta) ? 1 : 0;
        if (iter==0 && vg > GS-2)        m = 1;
        if (new_stopped && g==action)    m = 0;
        if (allow && g==ai0_new)         m = 0;
        mask[(size_t)b*GS+g] = (unsigned char)m;
    }

    // ---- gather next GRU inputs (uses OLD stopped / OLD nol, per reference order)
    if (t < E){
        float v1 = h[((size_t)b*GS + action)*E + t];
        q1in[b*E+t] = v1;
        int i2 = nol_old % GS; if (i2<0) i2 += GS;
        float v2 = old_stopped ? v1 : h[((size_t)b*GS + i2)*E + t];
        q2in[b*E+t] = v2;
    }

    __syncthreads();
    if (t==0){
        int ai[4], kl[5], kr[4];
        for (int j=0;j<4;++j) ai[j]=st[2+j];
        for (int j=0;j<5;++j) kl[j]=st[6+j];
        for (int j=0;j<4;++j) kr[j]=st[11+j];
        float ll = __int_as_float(st[15]);

        ll += (iter==0) ? loss : (old_stopped ? 0.f : loss);
        ai[iter] = action;
        if (old_stopped)  kl[iter] = action;                 // old stopped
        if (!old_stopped) kr[(iter+3)&3] = action;           // old stopped
        kl[iter+1] = nna;
        if (new_stopped) kl[iter] = kl[(iter+4)%5];          // new stopped
        if (new_stopped) kr[iter] = kr[(iter+3)&3];          // new stopped
        int nol_new = new_stopped ? -1 : nna;

        if (iter == KMAXI-1){
            if (!new_stopped) kr[3] = kl[4];
            for (int j=0;j<4;++j) out[b*12+j]   = (float)ai[j];
            for (int j=0;j<4;++j) out[b*12+4+j] = (float)kl[j];
            for (int j=0;j<4;++j) out[b*12+8+j] = (float)kr[j];
            out[BS*12 + b] = ll;
        }
        st[0]=new_stopped; st[1]=nol_new;
        for (int j=0;j<4;++j) st[2+j]=ai[j];
        for (int j=0;j<5;++j) st[6+j]=kl[j];
        for (int j=0;j<4;++j) st[11+j]=kr[j];
        st[15]=__float_as_int(ll);
    }
}

// ----------------------------------------------------------------
extern "C" void kernel_launch(void* const* d_in, const int* in_sizes, int n_in,
                              void* d_out, int out_size, void* d_ws, size_t ws_size,
                              hipStream_t stream)
{
    const float* h            = (const float*)d_in[0];
    const int*   rec          = (const int*)  d_in[1];
    /* d_in[2] = context2, unused by reference */
    const int*   vtime        = (const int*)  d_in[3];
    const int*   last_action  = (const int*)  d_in[4];
    const int*   fixed_action = (const int*)  d_in[5];
    const float* WK1=(const float*)d_in[6],  *WK2=(const float*)d_in[7];
    const float* WK3=(const float*)d_in[8],  *WK4=(const float*)d_in[9];
    const float* WQ1=(const float*)d_in[10], *WQ2=(const float*)d_in[11];
    const float* WQ3=(const float*)d_in[12], *WQ4=(const float*)d_in[13];
    const float* W_init=(const float*)d_in[14];
    const float* b_init=(const float*)d_in[15];
    const float* V1=(const float*)d_in[16], *V2=(const float*)d_in[17];
    const float* init_query=(const float*)d_in[18];
    const float* Wih1=(const float*)d_in[19], *Whh1=(const float*)d_in[20];
    const float* bih1=(const float*)d_in[21], *bhh1=(const float*)d_in[22];
    const float* Wih2=(const float*)d_in[23], *Whh2=(const float*)d_in[24];
    const float* bih2=(const float*)d_in[25], *bhh2=(const float*)d_in[26];
    float* out = (float*)d_out;

    char* ws = (char*)d_ws;
    size_t off = 0;
    auto alloc = [&](size_t bytes)->char*{
        char* p = ws + off; off += (bytes + 255) & ~(size_t)255; return p;
    };
    bf16_t* M1t  = (bf16_t*)alloc((size_t)BS*E*E*sizeof(bf16_t));
    bf16_t* M2t  = (bf16_t*)alloc((size_t)BS*E*E*sizeof(bf16_t));
    float*  raw  = (float*) alloc((size_t)BS*GS*sizeof(float));
    int*    vtt  = (int*)   alloc((size_t)BS*GS*sizeof(int));
    unsigned char* mask = (unsigned char*)alloc((size_t)BS*GS);
    float*  hpart= (float*) alloc((size_t)BS*16*E*sizeof(float));
    float*  q1s  = (float*) alloc((size_t)BS*E*sizeof(float));
    float*  q2s  = (float*) alloc((size_t)BS*E*sizeof(float));
    float*  q1in = (float*) alloc((size_t)BS*E*sizeof(float));
    float*  q2in = (float*) alloc((size_t)BS*E*sizeof(float));
    float*  add1 = (float*) alloc((size_t)BS*E*sizeof(float));
    float*  add2 = (float*) alloc((size_t)BS*E*sizeof(float));
    int*    state= (int*)   alloc((size_t)BS*32*sizeof(int));
    (void)ws_size; (void)in_sizes; (void)n_in; (void)out_size;

    hipLaunchKernelGGL(k_hpart, dim3(BS,16), dim3(E), 0, stream, h, hpart);
    hipLaunchKernelGGL(k_setup, dim3(BS), dim3(E), 0, stream,
                       hpart, W_init, b_init, init_query, q1s,q2s,q1in,q2in, state, mask);
    for (int it=0; it<KMAXI; ++it){
        hipLaunchKernelGGL(k_gru, dim3(BS), dim3(E), 0, stream,
                           q1in,q2in,q1s,q2s,
                           Wih1,Whh1,bih1,bhh1, Wih2,Whh2,bih2,bhh2,
                           WQ1,WQ2,WQ3,WQ4, WK1,WK2,WK3,WK4,
                           add1,add2, M1t,M2t);
        hipLaunchKernelGGL(k_scores, dim3(32,BS), dim3(256), 0, stream,
                           h, M1t,M2t, add1,add2, V1,V2, raw);
        hipLaunchKernelGGL(k_step, dim3(BS), dim3(256), 0, stream,
                           it, raw, h, rec, vtime, last_action, fixed_action,
                           mask, vtt, state, q1in, q2in, out);
    }
}

// Round 2
// 734.721 us; speedup vs baseline: 1.5596x; 1.5596x over previous
//
#include <hip/hip_runtime.h>
#include <math.h>

#define BS 128
#define GS 2000
#define E  128
#define KMAXI 4
#define CLIPV 10.0f
#define NEGV  -1.0e30f

typedef __bf16 bf16_t;
typedef __bf16 bf16x8 __attribute__((ext_vector_type(8)));
typedef __bf16 bf16x4 __attribute__((ext_vector_type(4)));
typedef float fx4 __attribute__((ext_vector_type(4)));

__device__ __forceinline__ float fast_sigmoid(float x){ return 1.0f/(1.0f+__expf(-x)); }
__device__ __forceinline__ float fast_tanhf(float x){
    float e = __expf(2.0f*x);
    return 1.0f - 2.0f/(e + 1.0f);
}

// ---------------------------------------------------------------- h fp32 -> bf16 + mean partials (fused)
__global__ __launch_bounds__(256) void k_hconv(const float* __restrict__ h,
        bf16_t* __restrict__ hb, float* __restrict__ hpart)
{
    int b = blockIdx.x, p = blockIdx.y, tid = threadIdx.x;
    int e4 = (tid & 31) * 4;     // e-group of 4
    int gsub = tid >> 5;         // 8 g-lanes
    float4 acc = {0.f,0.f,0.f,0.f};
    int g0 = p*125, g1 = g0+125;             // 16*125 = 2000
    for (int g = g0 + gsub; g < g1; g += 8){
        const float* ph = h + ((size_t)b*GS + g)*E + e4;
        float4 v = *(const float4*)ph;
        acc.x += v.x; acc.y += v.y; acc.z += v.z; acc.w += v.w;
        bf16x4 o; o[0]=(bf16_t)v.x; o[1]=(bf16_t)v.y; o[2]=(bf16_t)v.z; o[3]=(bf16_t)v.w;
        *(bf16x4*)(hb + ((size_t)b*GS + g)*E + e4) = o;
    }
    __shared__ float ps[8][E];
    *(float4*)(&ps[gsub][e4]) = acc;
    __syncthreads();
    if (tid < E){
        float s = 0.f;
        #pragma unroll
        for (int j=0;j<8;++j) s += ps[j][tid];
        hpart[(b*16+p)*E + tid] = s;
    }
}

// ---------------------------------------------------------------- fallback h partial sums (fp32 path)
__global__ void k_hpart(const float* __restrict__ h, float* __restrict__ hpart){
    int b = blockIdx.x, p = blockIdx.y, t = threadIdx.x; // t in [0,128)
    float acc = 0.f;
    int g0 = p*125, g1 = g0+125;
    const float* hp = h + ((size_t)b*GS)*E + t;
    for (int g=g0; g<g1; ++g) acc += hp[(size_t)g*E];
    hpart[(b*16+p)*E + t] = acc;
}

// ---------------------------------------------------------------- qinit + state/mask init
__global__ void k_setup(const float* __restrict__ hpart,
                        const float* __restrict__ W_init, const float* __restrict__ b_init,
                        const float* __restrict__ init_query,
                        float* __restrict__ q1s, float* __restrict__ q2s,
                        float* __restrict__ q1in, float* __restrict__ q2in,
                        int* __restrict__ state, unsigned char* __restrict__ mask)
{
    int b = blockIdx.x, t = threadIdx.x; // 128 threads
    __shared__ float hm[E];
    float s = 0.f;
    for (int p=0;p<16;++p) s += hpart[(b*16+p)*E + t];
    hm[t] = s * (1.0f/(float)GS);
    __syncthreads();
    float acc = b_init[t];
    const float4* w4 = (const float4*)(W_init + (size_t)t*E);
    const float4* h4 = (const float4*)hm;
    for (int i=0;i<32;++i){
        float4 w=w4[i], x=h4[i];
        acc += w.x*x.x + w.y*x.y + w.z*x.z + w.w*x.w;
    }
    q1s[b*E+t]=acc; q2s[b*E+t]=acc;
    float iq = init_query[t];
    q1in[b*E+t]=iq; q2in[b*E+t]=iq;
    for (int g=t; g<GS; g+=E) mask[(size_t)b*GS+g]=0;
    if (t==0){
        int* st = state + b*32;
        st[0]=1;            // stopped = True (initial)
        st[1]=-1;           // nol
        for (int j=2;j<15;++j) st[j]=0;  // ai[4], kl[5], kr[4]
        st[15]=__float_as_int(0.0f);     // ll
    }
}

// ---------------------------------------------------------------- GRU both halves in parallel + projections + combined matrices
__global__ __launch_bounds__(256) void k_gru(
    const float* __restrict__ q1in, const float* __restrict__ q2in,
    float* __restrict__ q1s, float* __restrict__ q2s,
    const float* __restrict__ Wih1, const float* __restrict__ Whh1,
    const float* __restrict__ bih1, const float* __restrict__ bhh1,
    const float* __restrict__ Wih2, const float* __restrict__ Whh2,
    const float* __restrict__ bih2, const float* __restrict__ bhh2,
    const float* __restrict__ WQ1, const float* __restrict__ WQ2,
    const float* __restrict__ WQ3, const float* __restrict__ WQ4,
    const float* __restrict__ WK1, const float* __restrict__ WK2,
    const float* __restrict__ WK3, const float* __restrict__ WK4,
    float* __restrict__ add1, float* __restrict__ add2,
    bf16_t* __restrict__ M1t, bf16_t* __restrict__ M2t)
{
    __shared__ float xs[2][E], hs[2][E], qn[2][E], mulv[2][E];
    int b = blockIdx.x, tid = threadIdx.x;
    int half = tid >> 7, t = tid & 127;
    const float* qin = half ? q2in : q1in;
    float*       qs  = half ? q2s  : q1s;
    const float* Wih = half ? Wih2 : Wih1;
    const float* Whh = half ? Whh2 : Whh1;
    const float* bih = half ? bih2 : bih1;
    const float* bhh = half ? bhh2 : bhh1;
    const float* WQa = half ? WQ2 : WQ1;
    const float* WQm = half ? WQ4 : WQ3;
    const float* WKa = half ? WK2 : WK1;
    const float* WKm = half ? WK4 : WK3;
    float*       addv= half ? add2 : add1;
    bf16_t*      Mt  = half ? M2t  : M1t;

    xs[half][t] = qin[b*E+t];
    hs[half][t] = qs[b*E+t];
    __syncthreads();

    float gr=bih[t], gz=bih[t+E], gn=bih[t+2*E];
    float hr=bhh[t], hz=bhh[t+E], hn=bhh[t+2*E];
    {
        const float4* x4 = (const float4*)xs[half];
        const float4* h4 = (const float4*)hs[half];
        const float4* wr=(const float4*)(Wih+(size_t)t*E);
        const float4* wz=(const float4*)(Wih+(size_t)(t+E)*E);
        const float4* wn=(const float4*)(Wih+(size_t)(t+2*E)*E);
        const float4* vr=(const float4*)(Whh+(size_t)t*E);
        const float4* vz=(const float4*)(Whh+(size_t)(t+E)*E);
        const float4* vn=(const float4*)(Whh+(size_t)(t+2*E)*E);
        #pragma unroll 4
        for (int i=0;i<32;++i){
            float4 x=x4[i], h0=h4[i];
            float4 a=wr[i];  gr += x.x*a.x + x.y*a.y + x.z*a.z + x.w*a.w;
            float4 bq=wz[i]; gz += x.x*bq.x + x.y*bq.y + x.z*bq.z + x.w*bq.w;
            float4 cq=wn[i]; gn += x.x*cq.x + x.y*cq.y + x.z*cq.z + x.w*cq.w;
            float4 d=vr[i];  hr += h0.x*d.x + h0.y*d.y + h0.z*d.z + h0.w*d.w;
            float4 e=vz[i];  hz += h0.x*e.x + h0.y*e.y + h0.z*e.z + h0.w*e.w;
            float4 f=vn[i];  hn += h0.x*f.x + h0.y*f.y + h0.z*f.z + h0.w*f.w;
        }
    }
    float r = fast_sigmoid(gr+hr);
    float z = fast_sigmoid(gz+hz);
    float n = fast_tanhf(gn + r*hn);
    float hnew = (1.f-z)*n + z*hs[half][t];
    qn[half][t] = hnew; qs[b*E+t] = hnew;
    __syncthreads();

    float a=0.f, m=0.f;
    {
        const float4* q4 = (const float4*)qn[half];
        const float4* wa=(const float4*)(WQa+(size_t)t*E);
        const float4* wm=(const float4*)(WQm+(size_t)t*E);
        #pragma unroll 4
        for (int i=0;i<32;++i){
            float4 qv=q4[i];
            float4 a4=wa[i]; a += qv.x*a4.x + qv.y*a4.y + qv.z*a4.z + qv.w*a4.w;
            float4 m4=wm[i]; m += qv.x*m4.x + qv.y*m4.y + qv.z*m4.z + qv.w*m4.w;
        }
    }
    addv[b*E+t] = a; mulv[half][t] = m;
    __syncthreads();

    // M[f][e] = WKa[f,e] + WKm[f,e]*mul[f], bf16, [f][e] row-major
    int eg = (t & 31) * 4;   // e-offset
    int fo = t >> 5;         // 0..3
    for (int f0=0; f0<E; f0+=4){
        int f = f0 + fo;
        float mf = mulv[half][f];
        float4 wa_ = *(const float4*)(WKa + (size_t)f*E + eg);
        float4 wm_ = *(const float4*)(WKm + (size_t)f*E + eg);
        bf16x4 o;
        o[0]=(bf16_t)(wa_.x + wm_.x*mf);
        o[1]=(bf16_t)(wa_.y + wm_.y*mf);
        o[2]=(bf16_t)(wa_.z + wm_.z*mf);
        o[3]=(bf16_t)(wa_.w + wm_.w*mf);
        *(bf16x4*)(Mt + ((size_t)(b*E+f))*E + eg) = o;
    }
}

// ---------------------------------------------------------------- scores: LDS-staged M, 64 g/wave, bf16 h
template<bool HB>
__global__ __launch_bounds__(256,2) void k_scores(
    const float* __restrict__ hf, const bf16_t* __restrict__ hb,
    const bf16_t* __restrict__ M1t, const bf16_t* __restrict__ M2t,
    const float* __restrict__ add1, const float* __restrict__ add2,
    const float* __restrict__ V1, const float* __restrict__ V2,
    float* __restrict__ raw)
{
    constexpr int LDW = 136;   // padded row stride (elements) to balance LDS banks
    __shared__ bf16_t sM1[E*LDW];
    __shared__ bf16_t sM2[E*LDW];
    int b   = blockIdx.y;
    int tid = threadIdx.x;

    // ---- stage M1/M2 into LDS (coalesced 16B global reads)
    {
        const bf16x8* g1 = (const bf16x8*)(M1t + (size_t)b*E*E);
        const bf16x8* g2 = (const bf16x8*)(M2t + (size_t)b*E*E);
        #pragma unroll
        for (int k=0;k<8;++k){
            int u = tid + k*256;            // 0..2047
            int f = u >> 4, eu = u & 15;
            bf16x8 v1 = g1[u];
            bf16x8 v2 = g2[u];
            *(bf16x8*)(sM1 + f*LDW + eu*8) = v1;
            *(bf16x8*)(sM2 + f*LDW + eu*8) = v2;
        }
    }

    int wave = tid >> 6, lane = tid & 63;
    int qd = lane >> 4, c = lane & 15;
    int gbase = blockIdx.x*256 + wave*64;

    // ---- A fragments: 4 sets x 16 rows, full K=128 (overlaps staging latency)
    bf16x8 afr[4][4];
    #pragma unroll
    for (int set=0; set<4; ++set){
        int grow = gbase + set*16 + c;
        if (grow >= GS) grow = GS-1;
        if (HB){
            const bf16x8* hp = (const bf16x8*)(hb + ((size_t)b*GS + grow)*E);
            #pragma unroll
            for (int s=0;s<4;++s) afr[set][s] = hp[s*4 + qd];
        } else {
            const float* hrow = hf + ((size_t)b*GS + grow)*E;
            #pragma unroll
            for (int s=0;s<4;++s){
                const float* p = hrow + s*32 + qd*8;
                float4 u0 = *(const float4*)(p);
                float4 u1 = *(const float4*)(p+4);
                bf16x8 a;
                a[0]=(bf16_t)u0.x; a[1]=(bf16_t)u0.y; a[2]=(bf16_t)u0.z; a[3]=(bf16_t)u0.w;
                a[4]=(bf16_t)u1.x; a[5]=(bf16_t)u1.y; a[6]=(bf16_t)u1.z; a[7]=(bf16_t)u1.w;
                afr[set][s]=a;
            }
        }
    }

    // ---- preload per-f constants for this lane's f = tf*16+c
    float av1[8], av2[8], vv1[8], vv2[8];
    #pragma unroll
    for (int tf=0; tf<8; ++tf){
        int f = tf*16 + c;
        av1[tf] = add1[b*E+f]; av2[tf] = add2[b*E+f];
        vv1[tf] = V1[f];       vv2[tf] = V2[f];
    }

    __syncthreads();

    float sp[4][4];
    #pragma unroll
    for (int set=0;set<4;++set)
        #pragma unroll
        for (int r=0;r<4;++r) sp[set][r]=0.f;

    #pragma unroll
    for (int tf=0; tf<8; ++tf){
        int f = tf*16 + c;
        bf16x8 b1[4], b2[4];
        #pragma unroll
        for (int s=0;s<4;++s){
            b1[s] = *(const bf16x8*)(sM1 + f*LDW + s*32 + qd*8);
            b2[s] = *(const bf16x8*)(sM2 + f*LDW + s*32 + qd*8);
        }
        fx4 acc[4][2];
        #pragma unroll
        for (int set=0;set<4;++set){ acc[set][0]=(fx4){0,0,0,0}; acc[set][1]=(fx4){0,0,0,0}; }
        #pragma unroll
        for (int s=0;s<4;++s){
            #pragma unroll
            for (int set=0;set<4;++set){
                acc[set][0] = __builtin_amdgcn_mfma_f32_16x16x32_bf16(afr[set][s], b1[s], acc[set][0], 0,0,0);
                acc[set][1] = __builtin_amdgcn_mfma_f32_16x16x32_bf16(afr[set][s], b2[s], acc[set][1], 0,0,0);
            }
        }
        #pragma unroll
        for (int set=0;set<4;++set){
            #pragma unroll
            for (int r=0;r<4;++r){
                sp[set][r] += vv1[tf]*fast_tanhf(acc[set][0][r]+av1[tf])
                            + vv2[tf]*fast_tanhf(acc[set][1][r]+av2[tf]);
            }
        }
    }

    // ---- reduce over the 16 f-lanes of each quad, store float4 per (set,qd)
    #pragma unroll
    for (int set=0;set<4;++set){
        float v[4];
        #pragma unroll
        for (int r=0;r<4;++r){
            float s = sp[set][r];
            s += __shfl_xor(s, 1); s += __shfl_xor(s, 2);
            s += __shfl_xor(s, 4); s += __shfl_xor(s, 8);
            v[r] = s;
        }
        if (c==0){
            int g = gbase + set*16 + qd*4;
            if (g+3 < GS){
                float4 o;
                o.x = CLIPV*fast_tanhf(v[0]);
                o.y = CLIPV*fast_tanhf(v[1]);
                o.z = CLIPV*fast_tanhf(v[2]);
                o.w = CLIPV*fast_tanhf(v[3]);
                *(float4*)(raw + (size_t)b*GS + g) = o;
            }
        }
    }
}

// ---------------------------------------------------------------- per-step: log-softmax + bookkeeping
__global__ void k_step(int iter,
    const float* __restrict__ raw, const float* __restrict__ h,
    const int* __restrict__ rec, const int* __restrict__ vtime,
    const int* __restrict__ last_action, const int* __restrict__ fixed_action,
    unsigned char* __restrict__ mask, int* __restrict__ vtt,
    int* __restrict__ state, float* __restrict__ q1in, float* __restrict__ q2in,
    float* __restrict__ out)
{
    int b = blockIdx.x, t = threadIdx.x;   // 256 threads
    __shared__ float red[256];
    int* st = state + b*32;
    int old_stopped = st[0];
    int nol_old     = st[1];
    int ai0_old     = st[2];
    int la          = last_action[b];

    int action;
    if (iter==0) action = fixed_action[b*KMAXI];
    else         action = old_stopped ? ai0_old : fixed_action[b*KMAXI+iter];

    // ---- logsumexp over masked logits (mask is from previous iteration)
    float mx = -3.0e38f;
    for (int g=t; g<GS; g+=256){
        float l = raw[(size_t)b*GS+g];
        if (mask[(size_t)b*GS+g]) l = NEGV;
        if (iter==0 && g==la)     l = NEGV;
        mx = fmaxf(mx, l);
    }
    red[t]=mx; __syncthreads();
    for (int s=128;s>0;s>>=1){ if(t<s) red[t]=fmaxf(red[t],red[t+s]); __syncthreads(); }
    mx = red[0]; __syncthreads();
    float sm = 0.f;
    for (int g=t; g<GS; g+=256){
        float l = raw[(size_t)b*GS+g];
        if (mask[(size_t)b*GS+g]) l = NEGV;
        if (iter==0 && g==la)     l = NEGV;
        sm += __expf(l-mx);
    }
    red[t]=sm; __syncthreads();
    for (int s=128;s>0;s>>=1){ if(t<s) red[t]+=red[t+s]; __syncthreads(); }
    float lse = mx + __logf(red[0]);
    __syncthreads();

    float al = raw[(size_t)b*GS+action];
    if (mask[(size_t)b*GS+action]) al = NEGV;
    if (iter==0 && action==la)     al = NEGV;
    float loss = al - lse;

    int nna = rec[(size_t)b*GS+action];
    int eq  = (action == nol_old) ? 1 : 0;
    int new_stopped = (iter==0) ? eq : (old_stopped | eq);
    int ai0_new = (iter==0) ? action : ai0_old;
    int allow = (!new_stopped) && (nna == ai0_new);

    __syncthreads();   // everyone done READING old mask before anyone writes new mask

    // ---- vtt (computed once at iter 0, Python-mod semantics)
    if (iter==0){
        int va = vtime[(size_t)b*GS+action];
        for (int g=t; g<GS; g+=256){
            int d = vtime[(size_t)b*GS+g] - va;
            d %= GS; if (d<0) d += GS;
            vtt[(size_t)b*GS+g] = d;           // same-thread partition as mask loop below
        }
    }
    int vta = (iter==0) ? 0 : vtt[(size_t)b*GS+action];

    // ---- new mask
    for (int g=t; g<GS; g+=256){
        int vg = vtt[(size_t)b*GS+g];
        int m = (vg <= vta) ? 1 : 0;
        if (iter==0 && vg > GS-2)        m = 1;
        if (new_stopped && g==action)    m = 0;
        if (allow && g==ai0_new)         m = 0;
        mask[(size_t)b*GS+g] = (unsigned char)m;
    }

    // ---- gather next GRU inputs (uses OLD stopped / OLD nol, per reference order)
    if (t < E){
        float v1 = h[((size_t)b*GS + action)*E + t];
        q1in[b*E+t] = v1;
        int i2 = nol_old % GS; if (i2<0) i2 += GS;
        float v2 = old_stopped ? v1 : h[((size_t)b*GS + i2)*E + t];
        q2in[b*E+t] = v2;
    }

    __syncthreads();
    if (t==0){
        int ai[4], kl[5], kr[4];
        for (int j=0;j<4;++j) ai[j]=st[2+j];
        for (int j=0;j<5;++j) kl[j]=st[6+j];
        for (int j=0;j<4;++j) kr[j]=st[11+j];
        float ll = __int_as_float(st[15]);

        ll += (iter==0) ? loss : (old_stopped ? 0.f : loss);
        ai[iter] = action;
        if (old_stopped)  kl[iter] = action;                 // old stopped
        if (!old_stopped) kr[(iter+3)&3] = action;           // old stopped
        kl[iter+1] = nna;
        if (new_stopped) kl[iter] = kl[(iter+4)%5];          // new stopped
        if (new_stopped) kr[iter] = kr[(iter+3)&3];          // new stopped
        int nol_new = new_stopped ? -1 : nna;

        if (iter == KMAXI-1){
            if (!new_stopped) kr[3] = kl[4];
            for (int j=0;j<4;++j) out[b*12+j]   = (float)ai[j];
            for (int j=0;j<4;++j) out[b*12+4+j] = (float)kl[j];
            for (int j=0;j<4;++j) out[b*12+8+j] = (float)kr[j];
            out[BS*12 + b] = ll;
        }
        st[0]=new_stopped; st[1]=nol_new;
        for (int j=0;j<4;++j) st[2+j]=ai[j];
        for (int j=0;j<5;++j) st[6+j]=kl[j];
        for (int j=0;j<4;++j) st[11+j]=kr[j];
        st[15]=__float_as_int(ll);
    }
}

// ----------------------------------------------------------------
extern "C" void kernel_launch(void* const* d_in, const int* in_sizes, int n_in,
                              void* d_out, int out_size, void* d_ws, size_t ws_size,
                              hipStream_t stream)
{
    const float* h            = (const float*)d_in[0];
    const int*   rec          = (const int*)  d_in[1];
    /* d_in[2] = context2, unused by reference */
    const int*   vtime        = (const int*)  d_in[3];
    const int*   last_action  = (const int*)  d_in[4];
    const int*   fixed_action = (const int*)  d_in[5];
    const float* WK1=(const float*)d_in[6],  *WK2=(const float*)d_in[7];
    const float* WK3=(const float*)d_in[8],  *WK4=(const float*)d_in[9];
    const float* WQ1=(const float*)d_in[10], *WQ2=(const float*)d_in[11];
    const float* WQ3=(const float*)d_in[12], *WQ4=(const float*)d_in[13];
    const float* W_init=(const float*)d_in[14];
    const float* b_init=(const float*)d_in[15];
    const float* V1=(const float*)d_in[16], *V2=(const float*)d_in[17];
    const float* init_query=(const float*)d_in[18];
    const float* Wih1=(const float*)d_in[19], *Whh1=(const float*)d_in[20];
    const float* bih1=(const float*)d_in[21], *bhh1=(const float*)d_in[22];
    const float* Wih2=(const float*)d_in[23], *Whh2=(const float*)d_in[24];
    const float* bih2=(const float*)d_in[25], *bhh2=(const float*)d_in[26];
    float* out = (float*)d_out;

    char* ws = (char*)d_ws;
    size_t off = 0;
    auto alloc = [&](size_t bytes)->char*{
        char* p = ws + off; off += (bytes + 255) & ~(size_t)255; return p;
    };
    bf16_t* M1t  = (bf16_t*)alloc((size_t)BS*E*E*sizeof(bf16_t));
    bf16_t* M2t  = (bf16_t*)alloc((size_t)BS*E*E*sizeof(bf16_t));
    float*  raw  = (float*) alloc((size_t)BS*GS*sizeof(float));
    int*    vtt  = (int*)   alloc((size_t)BS*GS*sizeof(int));
    unsigned char* mask = (unsigned char*)alloc((size_t)BS*GS);
    float*  hpart= (float*) alloc((size_t)BS*16*E*sizeof(float));
    float*  q1s  = (float*) alloc((size_t)BS*E*sizeof(float));
    float*  q2s  = (float*) alloc((size_t)BS*E*sizeof(float));
    float*  q1in = (float*) alloc((size_t)BS*E*sizeof(float));
    float*  q2in = (float*) alloc((size_t)BS*E*sizeof(float));
    float*  add1 = (float*) alloc((size_t)BS*E*sizeof(float));
    float*  add2 = (float*) alloc((size_t)BS*E*sizeof(float));
    int*    state= (int*)   alloc((size_t)BS*32*sizeof(int));

    size_t hb_bytes = (size_t)BS*GS*E*sizeof(bf16_t);
    bool use_hb = (off + hb_bytes + 256) <= ws_size;
    bf16_t* hb = use_hb ? (bf16_t*)alloc(hb_bytes) : nullptr;
    (void)in_sizes; (void)n_in; (void)out_size;

    if (use_hb){
        hipLaunchKernelGGL(k_hconv, dim3(BS,16), dim3(256), 0, stream, h, hb, hpart);
    } else {
        hipLaunchKernelGGL(k_hpart, dim3(BS,16), dim3(E), 0, stream, h, hpart);
    }
    hipLaunchKernelGGL(k_setup, dim3(BS), dim3(E), 0, stream,
                       hpart, W_init, b_init, init_query, q1s,q2s,q1in,q2in, state, mask);
    for (int it=0; it<KMAXI; ++it){
        hipLaunchKernelGGL(k_gru, dim3(BS), dim3(256), 0, stream,
                           q1in,q2in,q1s,q2s,
                           Wih1,Whh1,bih1,bhh1, Wih2,Whh2,bih2,bhh2,
                           WQ1,WQ2,WQ3,WQ4, WK1,WK2,WK3,WK4,
                           add1,add2, M1t,M2t);
        if (use_hb){
            hipLaunchKernelGGL((k_scores<true>), dim3(8,BS), dim3(256), 0, stream,
                               h, hb, M1t,M2t, add1,add2, V1,V2, raw);
        } else {
            hipLaunchKernelGGL((k_scores<false>), dim3(8,BS), dim3(256), 0, stream,
                               h, hb, M1t,M2t, add1,add2, V1,V2, raw);
        }
        hipLaunchKernelGGL(k_step, dim3(BS), dim3(256), 0, stream,
                           it, raw, h, rec, vtime, last_action, fixed_action,
                           mask, vtt, state, q1in, q2in, out);
    }
}